// Round 11
// baseline (927.851 us; speedup 1.0000x reference)
//
#include <hip/hip_runtime.h>
#include <hip/hip_cooperative_groups.h>

namespace cg = cooperative_groups;

#define N_NODES 50000
#define N_EDGES 800000
#define COOP_BLOCKS 1024
#define COOP_NT (COOP_BLOCKS * 256)

typedef __attribute__((ext_vector_type(8))) short bf16x8;
typedef __attribute__((ext_vector_type(4))) float f32x4;

#if __has_builtin(__builtin_amdgcn_fdot2_f32_bf16)
#define HAVE_FDOT2 1
typedef __attribute__((ext_vector_type(2))) __bf16 bf16v2;
#else
#define HAVE_FDOT2 0
#endif

__device__ inline unsigned short f2bf(float f) {
  unsigned int u = __float_as_uint(f);
  unsigned int r = u + 0x7FFFu + ((u >> 16) & 1u);
  return (unsigned short)(r >> 16);
}
__device__ inline float bf_lo(unsigned int u) { return __uint_as_float(u << 16); }
__device__ inline float bf_hi(unsigned int u) { return __uint_as_float(u & 0xffff0000u); }

__device__ inline int block_excl_scan_256(int v, int& total) {
  __shared__ int lds[8];
  int lane = threadIdx.x & 63, wid = threadIdx.x >> 6;
  int orig = v;
#pragma unroll
  for (int off = 1; off < 64; off <<= 1) {
    int t = __shfl_up(v, off);
    if (lane >= off) v += t;
  }
  if (lane == 63) lds[wid] = v;
  __syncthreads();
  if (threadIdx.x == 0) {
    int s = 0;
    for (int w = 0; w < 4; ++w) { int t = lds[w]; lds[w] = s; s += t; }
    lds[4] = s;
  }
  __syncthreads();
  total = lds[4];
  return v + lds[wid] - orig;   // exclusive
}

struct WPack { const float* W[8]; const float* B[8]; };

// ---------------- fused setup: zero+prep_w || hist -> scan -> scatter ----------------
// i64 detection: under int64 layout odd int32 words are the (zero) high halves;
// under int32 they are random node ids. 8 probes => P(false i64) ~ (2e-5)^8.
__global__ __launch_bounds__(256) void build_all(const int* __restrict__ ei,
                                                 int* __restrict__ cnt,
                                                 int* __restrict__ rowp,
                                                 int* __restrict__ cursor,
                                                 int* __restrict__ part,
                                                 int* __restrict__ ssrc,
                                                 WPack pk,
                                                 unsigned short* __restrict__ bt_all,
                                                 float* __restrict__ bcat_all) {
  cg::grid_group grid = cg::this_grid();
  const int tid = blockIdx.x * 256 + threadIdx.x;
  bool is64 = true;
#pragma unroll
  for (int i = 1; i < 16; i += 2) is64 = is64 && (ei[i] == 0);

  // phase A: zero histogram + weight prep (independent)
  for (int i = tid; i < N_NODES; i += COOP_NT) cnt[i] = 0;
  if (tid < 131072) {
    int lay = tid >> 16;
    int r = tid & 65535;
    int col = r >> 7, kk = r & 127;
    int sel = col >> 7, c = col & 127;
    int idx = lay * 4 + sel;
    bt_all[(size_t)lay * 65536 + col * 128 + kk] = f2bf(pk.W[idx][kk * 128 + c]);
    if (kk == 0) bcat_all[lay * 512 + col] = pk.B[idx][c];
  }
  grid.sync();

  // phase B: histogram of destinations
  for (int e = tid; e < N_EDGES; e += COOP_NT) {
    int d = is64 ? ei[2 * (N_EDGES + e)] : ei[N_EDGES + e];
    atomicAdd(&cnt[d], 1);
  }
  grid.sync();

  // phase C1: per-block exclusive scans (196 blocks cover 50176 >= N_NODES)
  if (blockIdx.x < 196) {
    int i = blockIdx.x * 256 + threadIdx.x;
    int v = (i < N_NODES) ? cnt[i] : 0;
    int total;
    int ex = block_excl_scan_256(v, total);
    if (i < N_NODES) rowp[i] = ex;
    if (threadIdx.x == 0) part[blockIdx.x] = total;
  }
  grid.sync();

  // phase C2: scan the 196 partials
  if (blockIdx.x == 0) {
    int i = threadIdx.x;
    int v = (i < 196) ? part[i] : 0;
    int total;
    int ex = block_excl_scan_256(v, total);
    if (i < 196) part[i] = ex;
  }
  grid.sync();

  // phase C3: add block offsets -> rowp, cursor
  if (blockIdx.x < 196) {
    int i = blockIdx.x * 256 + threadIdx.x;
    if (i < N_NODES) {
      int v = rowp[i] + part[blockIdx.x];
      rowp[i] = v;
      cursor[i] = v;
    }
    if (i == 0) rowp[N_NODES] = N_EDGES;
  }
  grid.sync();

  // phase D: scatter sources into CSR order
  for (int e = tid; e < N_EDGES; e += COOP_NT) {
    int s, d;
    if (is64) { s = ei[2 * e]; d = ei[2 * (N_EDGES + e)]; }
    else      { s = ei[e];     d = ei[N_EDGES + e]; }
    int p = atomicAdd(&cursor[d], 1);
    ssrc[p] = s;
  }
}

// ---------------- GEMM: [50000x128] @ [128x512] (R8 structure) ----------------
// wave job: 64-col group x 80 rows (5 x 16-row tiles), B loaded once per wave.
// Outputs: q (cols 0..127)   -> Oqs bf16 [N][256] first half
//          s (cols 384..511) -> Oqs bf16 [N][256] second half
//          k (128..255), v (256..383) -> Okv bf16 [N][256] interleaved:
//              entry 4t+0=k(2t) 4t+1=k(2t+1) 4t+2=v(2t) 4t+3=v(2t+1)
template <bool AF32>
__global__ __launch_bounds__(256) void gemm_qkvs(const void* __restrict__ xa,
                                                 const unsigned short* __restrict__ bt,
                                                 const float* __restrict__ bias,
                                                 unsigned short* __restrict__ Oqs,
                                                 unsigned short* __restrict__ Okv) {
  const int wid = threadIdx.x >> 6;
  const int lane = threadIdx.x & 63;
  const int gw = blockIdx.x * 4 + wid;       // 0..4999
  const int colGroup = gw & 7;               // 8 col groups of 64
  const int rowGroup = gw >> 3;              // 0..624 (x5 row tiles)
  const int col0 = colGroup * 64;
  const int r = lane & 15;
  const int half = lane >> 4;                // 0..3

  bf16x8 bfrag[4][4];                        // [ct][kc]
#pragma unroll
  for (int ct = 0; ct < 4; ++ct) {
    int col = col0 + ct * 16 + r;
    const unsigned short* bp = bt + col * 128 + half * 8;
#pragma unroll
    for (int kc = 0; kc < 4; ++kc)
      bfrag[ct][kc] = *(const bf16x8*)(bp + kc * 32);
  }

#pragma unroll 1
  for (int rt = 0; rt < 5; ++rt) {
    int m0 = (rowGroup * 5 + rt) * 16;
    bf16x8 afrag[4];
    if constexpr (AF32) {
      const float* ap = (const float*)xa + (size_t)(m0 + r) * 128 + half * 8;
#pragma unroll
      for (int kc = 0; kc < 4; ++kc) {
        float4 f0 = *(const float4*)(ap + kc * 32);
        float4 f1 = *(const float4*)(ap + kc * 32 + 4);
        bf16x8 fr;
        fr[0] = (short)f2bf(f0.x); fr[1] = (short)f2bf(f0.y);
        fr[2] = (short)f2bf(f0.z); fr[3] = (short)f2bf(f0.w);
        fr[4] = (short)f2bf(f1.x); fr[5] = (short)f2bf(f1.y);
        fr[6] = (short)f2bf(f1.z); fr[7] = (short)f2bf(f1.w);
        afrag[kc] = fr;
      }
    } else {
      const unsigned short* ap = (const unsigned short*)xa + (size_t)(m0 + r) * 128 + half * 8;
#pragma unroll
      for (int kc = 0; kc < 4; ++kc) afrag[kc] = *(const bf16x8*)(ap + kc * 32);
    }

    f32x4 acc[4] = {{0.f,0.f,0.f,0.f},{0.f,0.f,0.f,0.f},{0.f,0.f,0.f,0.f},{0.f,0.f,0.f,0.f}};
#pragma unroll
    for (int ct = 0; ct < 4; ++ct)
#pragma unroll
      for (int kc = 0; kc < 4; ++kc)
        acc[ct] = __builtin_amdgcn_mfma_f32_16x16x32_bf16(afrag[kc], bfrag[ct][kc], acc[ct], 0, 0, 0);

    int orow = m0 + half * 4;
    if (colGroup < 2) {            // q -> Oqs[:, col]
#pragma unroll
      for (int ct = 0; ct < 4; ++ct) {
        int col = col0 + ct * 16 + r;
        float bv = bias[col];
#pragma unroll
        for (int j = 0; j < 4; ++j)
          Oqs[(size_t)(orow + j) * 256 + col] = f2bf(acc[ct][j] + bv);
      }
    } else if (colGroup >= 6) {    // s -> Oqs[:, 128 + c]
#pragma unroll
      for (int ct = 0; ct < 4; ++ct) {
        int col = col0 + ct * 16 + r;
        float bv = bias[col];
        int c = col - 384;
#pragma unroll
        for (int j = 0; j < 4; ++j)
          Oqs[(size_t)(orow + j) * 256 + 128 + c] = f2bf(acc[ct][j] + bv);
      }
    } else {                       // k or v -> Okv interleaved
      const int voff  = (colGroup >= 4) ? 2 : 0;
      const int cbase = (colGroup >= 4) ? 256 : 128;
#pragma unroll
      for (int ct = 0; ct < 4; ++ct) {
        int col = col0 + ct * 16 + r;
        float bv = bias[col];
        int c = col - cbase;
        int pos = ((c >> 1) << 2) + voff + (c & 1);
#pragma unroll
        for (int j = 0; j < 4; ++j)
          Okv[(size_t)(orow + j) * 256 + pos] = f2bf(acc[ct][j] + bv);
      }
    }
  }
}

// ---------------- edge attention: one wave per destination node ----------------
// Lane l owns channels 2l, 2l+1. One 8B kv gather per lane per edge, depth-4 pipeline.
template <int H, bool OUTBF>
__global__ __launch_bounds__(256, 8) void edge_attn(const unsigned short* __restrict__ Oqs,
                                                    const unsigned short* __restrict__ Okv,
                                                    const int* __restrict__ row_ptr,
                                                    const int* __restrict__ ssrc,
                                                    void* __restrict__ outp,
                                                    float scale) {
  int wid = threadIdx.x >> 6, lane = threadIdx.x & 63;
  int n = blockIdx.x * 4 + wid;
  if (n >= N_NODES) return;
  const unsigned int* qsw = (const unsigned int*)Oqs;  // node stride: 128 u32
  unsigned int qw = qsw[(size_t)n * 128 + lane];
#if HAVE_FDOT2
  const float esc = scale;              // q stays packed bf16; scale folded into exp arg
  bf16v2 qv = __builtin_bit_cast(bf16v2, qw);
#else
  float qx = bf_lo(qw) * scale, qy = bf_hi(qw) * scale;
#endif
  int start = row_ptr[n], end = row_ptr[n + 1];
  int len = end - start;
  const int* sp = ssrc + start;
  const uint2* kvb = (const uint2*)Okv;  // node stride: 64 uint2
  float acc0 = 0.f, acc1 = 0.f, den = 0.f;

  auto proc = [&](uint2 kv) {
#if HAVE_FDOT2
    float p = __builtin_amdgcn_fdot2_f32_bf16(__builtin_bit_cast(bf16v2, kv.x), qv, 0.f, false);
#else
    float p = qx * bf_lo(kv.x) + qy * bf_hi(kv.x);
#endif
#pragma unroll
    for (int off = 1; off < 64 / H; off <<= 1) p += __shfl_xor(p, off);
#if HAVE_FDOT2
    float e = __expf(p * esc);
#else
    float e = __expf(p);
#endif
    den += e; acc0 += e * bf_lo(kv.y); acc1 += e * bf_hi(kv.y);
  };

  int i = 0;
  if (len >= 4) {
    uint2 a = kvb[(size_t)sp[0] * 64 + lane];
    uint2 b = kvb[(size_t)sp[1] * 64 + lane];
    uint2 c = kvb[(size_t)sp[2] * 64 + lane];
    uint2 d = kvb[(size_t)sp[3] * 64 + lane];
    for (i = 4; i + 3 < len; i += 4) {
      uint2 na = kvb[(size_t)sp[i]     * 64 + lane];
      uint2 nb = kvb[(size_t)sp[i + 1] * 64 + lane];
      uint2 nc = kvb[(size_t)sp[i + 2] * 64 + lane];
      uint2 nd = kvb[(size_t)sp[i + 3] * 64 + lane];
      proc(a); proc(b); proc(c); proc(d);
      a = na; b = nb; c = nc; d = nd;
    }
    proc(a); proc(b); proc(c); proc(d);
  }
  for (; i < len; ++i) proc(kvb[(size_t)sp[i] * 64 + lane]);

  float inv = 1.0f / (den + 1e-16f);
  unsigned int sw = qsw[(size_t)n * 128 + 64 + lane];
  float r0 = acc0 * inv + bf_lo(sw);
  float r1 = acc1 * inv + bf_hi(sw);
  if (OUTBF) {  // layer 1: relu + pack bf16 directly for layer-2 GEMM input
    r0 = fmaxf(r0, 0.f); r1 = fmaxf(r1, 0.f);
    unsigned int pkv = (unsigned int)f2bf(r0) | ((unsigned int)f2bf(r1) << 16);
    ((unsigned int*)outp)[(size_t)n * 64 + lane] = pkv;
  } else {
    ((float2*)outp)[(size_t)n * 64 + lane] = make_float2(r0, r1);
  }
}

// ---------------- launch ----------------
extern "C" void kernel_launch(void* const* d_in, const int* in_sizes, int n_in,
                              void* d_out, int out_size, void* d_ws, size_t ws_size,
                              hipStream_t stream) {
  (void)in_sizes; (void)n_in; (void)out_size; (void)ws_size;
  const float* x  = (const float*)d_in[0];
  const int*   ei = (const int*)d_in[1];
  float* out = (float*)d_out;

  char* w = (char*)d_ws;
  size_t off = 0;
  auto alloc = [&](size_t b) { void* p = w + off; off += (b + 255) & ~(size_t)255; return p; };
  int* ssrc   = (int*)alloc((size_t)N_EDGES * 4);
  int* rowp   = (int*)alloc((size_t)(N_NODES + 1) * 4);
  int* cursor = (int*)alloc((size_t)N_NODES * 4);
  int* cnt    = (int*)alloc((size_t)N_NODES * 4);
  int* part   = (int*)alloc(256 * 4);
  unsigned short* xb  = (unsigned short*)alloc((size_t)N_NODES * 128 * 2);
  unsigned short* bt  = (unsigned short*)alloc((size_t)2 * 512 * 128 * 2);
  float* bcat = (float*)alloc(2 * 512 * 4);
  unsigned short* Oqs = (unsigned short*)alloc((size_t)N_NODES * 256 * 2);
  unsigned short* Okv = (unsigned short*)alloc((size_t)N_NODES * 256 * 2);

  WPack pk;
  for (int i = 0; i < 8; ++i) { pk.W[i] = (const float*)d_in[2 + 2 * i]; pk.B[i] = (const float*)d_in[3 + 2 * i]; }

  {
    void* args[] = { (void*)&ei, (void*)&cnt, (void*)&rowp, (void*)&cursor,
                     (void*)&part, (void*)&ssrc, (void*)&pk, (void*)&bt, (void*)&bcat };
    hipLaunchCooperativeKernel((void*)build_all, dim3(COOP_BLOCKS), dim3(256),
                               args, 0, stream);
  }

  // ---- layer 1 (H=4, d=32) ----
  gemm_qkvs<true><<<1250, 256, 0, stream>>>(x, bt, bcat, Oqs, Okv);
  edge_attn<4, true><<<12500, 256, 0, stream>>>(Oqs, Okv, rowp, ssrc, xb, 0.17677669529663689f);

  // ---- layer 2 (H=1, d=128) ----
  gemm_qkvs<false><<<1250, 256, 0, stream>>>(xb, bt + 65536, bcat + 512, Oqs, Okv);
  edge_attn<1, false><<<12500, 256, 0, stream>>>(Oqs, Okv, rowp, ssrc, out, 0.08838834764831845f);
}

// Round 12
// 398.760 us; speedup vs baseline: 2.3268x; 2.3268x over previous
//
#include <hip/hip_runtime.h>

#define N_NODES 50000
#define N_EDGES 800000

typedef __attribute__((ext_vector_type(8))) short bf16x8;
typedef __attribute__((ext_vector_type(4))) float f32x4;

#if __has_builtin(__builtin_amdgcn_fdot2_f32_bf16)
#define HAVE_FDOT2 1
typedef __attribute__((ext_vector_type(2))) __bf16 bf16v2;
#else
#define HAVE_FDOT2 0
#endif

__device__ inline unsigned short f2bf(float f) {
  unsigned int u = __float_as_uint(f);
  unsigned int r = u + 0x7FFFu + ((u >> 16) & 1u);
  return (unsigned short)(r >> 16);
}
__device__ inline float bf_lo(unsigned int u) { return __uint_as_float(u << 16); }
__device__ inline float bf_hi(unsigned int u) { return __uint_as_float(u & 0xffff0000u); }

// ---------------- CSR build directly from edge_index ----------------
// i64 detection per wave: under int64 layout every odd int32 word is 0; under int32
// layout those words are random node ids (P(all 64 == 0) ~ (2e-5)^64 = never).
__global__ void hist_direct(const int* __restrict__ ei, int* __restrict__ cnt) {
  int e = blockIdx.x * 256 + threadIdx.x;   // grid covers exactly N_EDGES
  int hi = ei[2 * e + 1];
  bool is64 = (__ballot(hi == 0) == 0xFFFFFFFFFFFFFFFFull);
  int d = is64 ? ei[2 * (N_EDGES + e)] : ei[N_EDGES + e];
  atomicAdd(&cnt[d], 1);
}

__global__ void scatter_direct(const int* __restrict__ ei, int* __restrict__ cursor,
                               int* __restrict__ ssrc) {
  int e = blockIdx.x * 256 + threadIdx.x;
  int hi = ei[2 * e + 1];
  bool is64 = (__ballot(hi == 0) == 0xFFFFFFFFFFFFFFFFull);
  int s, d;
  if (is64) { s = ei[2 * e]; d = ei[2 * (N_EDGES + e)]; }
  else      { s = ei[e];     d = ei[N_EDGES + e]; }
  int p = atomicAdd(&cursor[d], 1);
  ssrc[p] = s;
}

// ---------------- hierarchical coalesced scan ----------------
__device__ inline int block_excl_scan_256(int v, int& total) {
  __shared__ int lds[8];
  int lane = threadIdx.x & 63, wid = threadIdx.x >> 6;
  int orig = v;
#pragma unroll
  for (int off = 1; off < 64; off <<= 1) {
    int t = __shfl_up(v, off);
    if (lane >= off) v += t;
  }
  if (lane == 63) lds[wid] = v;
  __syncthreads();
  if (threadIdx.x == 0) {
    int s = 0;
    for (int w = 0; w < 4; ++w) { int t = lds[w]; lds[w] = s; s += t; }
    lds[4] = s;
  }
  __syncthreads();
  total = lds[4];
  return v + lds[wid] - orig;   // exclusive
}

__global__ __launch_bounds__(256) void scan1(const int* __restrict__ cnt,
                                             int* __restrict__ excl,
                                             int* __restrict__ partials) {
  int i = blockIdx.x * 256 + threadIdx.x;
  int v = (i < N_NODES) ? cnt[i] : 0;
  int total;
  int e = block_excl_scan_256(v, total);
  if (i < N_NODES) excl[i] = e;
  if (threadIdx.x == 0) partials[blockIdx.x] = total;
}

__global__ __launch_bounds__(256) void scan2(int* __restrict__ partials, int nb) {
  int i = threadIdx.x;
  int v = (i < nb) ? partials[i] : 0;
  int total;
  int e = block_excl_scan_256(v, total);
  if (i < nb) partials[i] = e;
}

__global__ __launch_bounds__(256) void scan3(int* __restrict__ row_ptr,
                                             const int* __restrict__ partials,
                                             int* __restrict__ cursor) {
  int i = blockIdx.x * 256 + threadIdx.x;
  if (i < N_NODES) {
    int v = row_ptr[i] + partials[blockIdx.x];
    row_ptr[i] = v;
    cursor[i] = v;
  }
  if (i == 0) row_ptr[N_NODES] = N_EDGES;
}

// ---------------- weight prep for BOTH layers in one launch ----------------
// bt_all[lay][col][k] bf16 (transposed weights), bcat_all[lay][col] f32.
struct WPack { const float* W[8]; const float* B[8]; };

__global__ void prep_w_both(WPack pk, unsigned short* __restrict__ bt_all,
                            float* __restrict__ bcat_all) {
  int t = blockIdx.x * 256 + threadIdx.x;  // 131072 threads
  int lay = t >> 16;
  int r = t & 65535;
  int col = r >> 7, kk = r & 127;
  int sel = col >> 7, c = col & 127;
  int idx = lay * 4 + sel;
  const float* W = pk.W[idx];
  bt_all[(size_t)lay * 65536 + col * 128 + kk] = f2bf(W[kk * 128 + c]);
  if (kk == 0) bcat_all[lay * 512 + col] = pk.B[idx][c];
}

// ---------------- GEMM: [50000x128] @ [128x512] (R8 shape + A-prefetch) ----------------
// wave job: 64-col group x 80 rows (5 x 16-row tiles); B loaded once per wave;
// A-tile for rt+1 prefetched before the MFMAs of rt (depth-2 pipeline).
// Outputs: q (cols 0..127)   -> Oqs bf16 [N][256] first half
//          s (cols 384..511) -> Oqs bf16 [N][256] second half
//          k (128..255), v (256..383) -> Okv bf16 [N][256] interleaved:
//              entry 4t+0=k(2t) 4t+1=k(2t+1) 4t+2=v(2t) 4t+3=v(2t+1)
template <bool AF32>
__device__ inline void load_a(const void* xa, int m0, int r, int half, bf16x8* fr4) {
  if constexpr (AF32) {
    const float* ap = (const float*)xa + (size_t)(m0 + r) * 128 + half * 8;
#pragma unroll
    for (int kc = 0; kc < 4; ++kc) {
      float4 f0 = *(const float4*)(ap + kc * 32);
      float4 f1 = *(const float4*)(ap + kc * 32 + 4);
      bf16x8 fr;
      fr[0] = (short)f2bf(f0.x); fr[1] = (short)f2bf(f0.y);
      fr[2] = (short)f2bf(f0.z); fr[3] = (short)f2bf(f0.w);
      fr[4] = (short)f2bf(f1.x); fr[5] = (short)f2bf(f1.y);
      fr[6] = (short)f2bf(f1.z); fr[7] = (short)f2bf(f1.w);
      fr4[kc] = fr;
    }
  } else {
    const unsigned short* ap = (const unsigned short*)xa + (size_t)(m0 + r) * 128 + half * 8;
#pragma unroll
    for (int kc = 0; kc < 4; ++kc) fr4[kc] = *(const bf16x8*)(ap + kc * 32);
  }
}

template <bool AF32>
__global__ __launch_bounds__(256) void gemm_qkvs(const void* __restrict__ xa,
                                                 const unsigned short* __restrict__ bt,
                                                 const float* __restrict__ bias,
                                                 unsigned short* __restrict__ Oqs,
                                                 unsigned short* __restrict__ Okv) {
  const int wid = threadIdx.x >> 6;
  const int lane = threadIdx.x & 63;
  const int gw = blockIdx.x * 4 + wid;       // 0..4999
  const int colGroup = gw & 7;               // 8 col groups of 64
  const int rowGroup = gw >> 3;              // 0..624 (x5 row tiles)
  const int col0 = colGroup * 64;
  const int r = lane & 15;
  const int half = lane >> 4;                // 0..3

  bf16x8 bfrag[4][4];                        // [ct][kc]
#pragma unroll
  for (int ct = 0; ct < 4; ++ct) {
    int col = col0 + ct * 16 + r;
    const unsigned short* bp = bt + col * 128 + half * 8;
#pragma unroll
    for (int kc = 0; kc < 4; ++kc)
      bfrag[ct][kc] = *(const bf16x8*)(bp + kc * 32);
  }

  bf16x8 aN[4];
  load_a<AF32>(xa, rowGroup * 5 * 16, r, half, aN);   // prefetch rt=0

#pragma unroll 1
  for (int rt = 0; rt < 5; ++rt) {
    int m0 = (rowGroup * 5 + rt) * 16;
    bf16x8 afrag[4];
#pragma unroll
    for (int kc = 0; kc < 4; ++kc) afrag[kc] = aN[kc];
    if (rt < 4) load_a<AF32>(xa, m0 + 16, r, half, aN);  // prefetch next tile

    f32x4 acc[4] = {{0.f,0.f,0.f,0.f},{0.f,0.f,0.f,0.f},{0.f,0.f,0.f,0.f},{0.f,0.f,0.f,0.f}};
#pragma unroll
    for (int ct = 0; ct < 4; ++ct)
#pragma unroll
      for (int kc = 0; kc < 4; ++kc)
        acc[ct] = __builtin_amdgcn_mfma_f32_16x16x32_bf16(afrag[kc], bfrag[ct][kc], acc[ct], 0, 0, 0);

    int orow = m0 + half * 4;
    if (colGroup < 2) {            // q -> Oqs[:, col]
#pragma unroll
      for (int ct = 0; ct < 4; ++ct) {
        int col = col0 + ct * 16 + r;
        float bv = bias[col];
#pragma unroll
        for (int j = 0; j < 4; ++j)
          Oqs[(size_t)(orow + j) * 256 + col] = f2bf(acc[ct][j] + bv);
      }
    } else if (colGroup >= 6) {    // s -> Oqs[:, 128 + c]
#pragma unroll
      for (int ct = 0; ct < 4; ++ct) {
        int col = col0 + ct * 16 + r;
        float bv = bias[col];
        int c = col - 384;
#pragma unroll
        for (int j = 0; j < 4; ++j)
          Oqs[(size_t)(orow + j) * 256 + 128 + c] = f2bf(acc[ct][j] + bv);
      }
    } else {                       // k or v -> Okv interleaved
      const int voff  = (colGroup >= 4) ? 2 : 0;
      const int cbase = (colGroup >= 4) ? 256 : 128;
#pragma unroll
      for (int ct = 0; ct < 4; ++ct) {
        int col = col0 + ct * 16 + r;
        float bv = bias[col];
        int c = col - cbase;
        int pos = ((c >> 1) << 2) + voff + (c & 1);
#pragma unroll
        for (int j = 0; j < 4; ++j)
          Okv[(size_t)(orow + j) * 256 + pos] = f2bf(acc[ct][j] + bv);
      }
    }
  }
}

// ---------------- edge attention: one wave per destination node ----------------
// Lane l owns channels 2l, 2l+1. One 8B kv gather per lane per edge, depth-4 pipeline.
template <int H, bool OUTBF>
__global__ __launch_bounds__(256, 8) void edge_attn(const unsigned short* __restrict__ Oqs,
                                                    const unsigned short* __restrict__ Okv,
                                                    const int* __restrict__ row_ptr,
                                                    const int* __restrict__ ssrc,
                                                    void* __restrict__ outp,
                                                    float scale) {
  int wid = threadIdx.x >> 6, lane = threadIdx.x & 63;
  int n = blockIdx.x * 4 + wid;
  if (n >= N_NODES) return;
  const unsigned int* qsw = (const unsigned int*)Oqs;  // node stride: 128 u32
  unsigned int qw = qsw[(size_t)n * 128 + lane];
#if HAVE_FDOT2
  const float esc = scale;              // q stays packed bf16; scale folded into exp arg
  bf16v2 qv = __builtin_bit_cast(bf16v2, qw);
#else
  float qx = bf_lo(qw) * scale, qy = bf_hi(qw) * scale;
#endif
  int start = row_ptr[n], end = row_ptr[n + 1];
  int len = end - start;
  const int* sp = ssrc + start;
  const uint2* kvb = (const uint2*)Okv;  // node stride: 64 uint2
  float acc0 = 0.f, acc1 = 0.f, den = 0.f;

  auto proc = [&](uint2 kv) {
#if HAVE_FDOT2
    float p = __builtin_amdgcn_fdot2_f32_bf16(__builtin_bit_cast(bf16v2, kv.x), qv, 0.f, false);
#else
    float p = qx * bf_lo(kv.x) + qy * bf_hi(kv.x);
#endif
#pragma unroll
    for (int off = 1; off < 64 / H; off <<= 1) p += __shfl_xor(p, off);
#if HAVE_FDOT2
    float e = __expf(p * esc);
#else
    float e = __expf(p);
#endif
    den += e; acc0 += e * bf_lo(kv.y); acc1 += e * bf_hi(kv.y);
  };

  int i = 0;
  if (len >= 4) {
    uint2 a = kvb[(size_t)sp[0] * 64 + lane];
    uint2 b = kvb[(size_t)sp[1] * 64 + lane];
    uint2 c = kvb[(size_t)sp[2] * 64 + lane];
    uint2 d = kvb[(size_t)sp[3] * 64 + lane];
    for (i = 4; i + 3 < len; i += 4) {
      uint2 na = kvb[(size_t)sp[i]     * 64 + lane];
      uint2 nb = kvb[(size_t)sp[i + 1] * 64 + lane];
      uint2 nc = kvb[(size_t)sp[i + 2] * 64 + lane];
      uint2 nd = kvb[(size_t)sp[i + 3] * 64 + lane];
      proc(a); proc(b); proc(c); proc(d);
      a = na; b = nb; c = nc; d = nd;
    }
    proc(a); proc(b); proc(c); proc(d);
  }
  for (; i < len; ++i) proc(kvb[(size_t)sp[i] * 64 + lane]);

  float inv = 1.0f / (den + 1e-16f);
  unsigned int sw = qsw[(size_t)n * 128 + 64 + lane];
  float r0 = acc0 * inv + bf_lo(sw);
  float r1 = acc1 * inv + bf_hi(sw);
  if (OUTBF) {  // layer 1: relu + pack bf16 directly for layer-2 GEMM input
    r0 = fmaxf(r0, 0.f); r1 = fmaxf(r1, 0.f);
    unsigned int pkv = (unsigned int)f2bf(r0) | ((unsigned int)f2bf(r1) << 16);
    ((unsigned int*)outp)[(size_t)n * 64 + lane] = pkv;
  } else {
    ((float2*)outp)[(size_t)n * 64 + lane] = make_float2(r0, r1);
  }
}

// ---------------- launch ----------------
extern "C" void kernel_launch(void* const* d_in, const int* in_sizes, int n_in,
                              void* d_out, int out_size, void* d_ws, size_t ws_size,
                              hipStream_t stream) {
  (void)in_sizes; (void)n_in; (void)out_size; (void)ws_size;
  const float* x  = (const float*)d_in[0];
  const int*   ei = (const int*)d_in[1];
  float* out = (float*)d_out;

  char* w = (char*)d_ws;
  size_t off = 0;
  auto alloc = [&](size_t b) { void* p = w + off; off += (b + 255) & ~(size_t)255; return p; };
  int* ssrc   = (int*)alloc((size_t)N_EDGES * 4);
  int* rowp   = (int*)alloc((size_t)(N_NODES + 1) * 4);
  int* cursor = (int*)alloc((size_t)N_NODES * 4);
  int* cnt    = (int*)alloc((size_t)N_NODES * 4);
  int* part   = (int*)alloc(256 * 4);
  unsigned short* xb  = (unsigned short*)alloc((size_t)N_NODES * 128 * 2);
  unsigned short* bt  = (unsigned short*)alloc((size_t)2 * 512 * 128 * 2);
  float* bcat = (float*)alloc(2 * 512 * 4);
  unsigned short* Oqs = (unsigned short*)alloc((size_t)N_NODES * 256 * 2);
  unsigned short* Okv = (unsigned short*)alloc((size_t)N_NODES * 256 * 2);

  WPack pk;
  for (int i = 0; i < 8; ++i) { pk.W[i] = (const float*)d_in[2 + 2 * i]; pk.B[i] = (const float*)d_in[3 + 2 * i]; }

  hipMemsetAsync(cnt, 0, (size_t)N_NODES * 4, stream);
  hist_direct<<<3125, 256, 0, stream>>>(ei, cnt);
  scan1<<<196, 256, 0, stream>>>(cnt, rowp, part);
  scan2<<<1, 256, 0, stream>>>(part, 196);
  scan3<<<196, 256, 0, stream>>>(rowp, part, cursor);
  scatter_direct<<<3125, 256, 0, stream>>>(ei, cursor, ssrc);
  prep_w_both<<<512, 256, 0, stream>>>(pk, bt, bcat);

  // ---- layer 1 (H=4, d=32) ----
  gemm_qkvs<true><<<1250, 256, 0, stream>>>(x, bt, bcat, Oqs, Okv);
  edge_attn<4, true><<<12500, 256, 0, stream>>>(Oqs, Okv, rowp, ssrc, xb, 0.17677669529663689f);

  // ---- layer 2 (H=1, d=128) ----
  gemm_qkvs<false><<<1250, 256, 0, stream>>>(xb, bt + 65536, bcat + 512, Oqs, Okv);
  edge_attn<1, false><<<12500, 256, 0, stream>>>(Oqs, Okv, rowp, ssrc, out, 0.08838834764831845f);
}

// Round 13
// 394.358 us; speedup vs baseline: 2.3528x; 1.0112x over previous
//
#include <hip/hip_runtime.h>

#define N_NODES 50000
#define N_EDGES 800000

typedef __attribute__((ext_vector_type(8))) short bf16x8;
typedef __attribute__((ext_vector_type(4))) float f32x4;

#if __has_builtin(__builtin_amdgcn_fdot2_f32_bf16)
#define HAVE_FDOT2 1
typedef __attribute__((ext_vector_type(2))) __bf16 bf16v2;
#else
#define HAVE_FDOT2 0
#endif

__device__ inline unsigned short f2bf(float f) {
  unsigned int u = __float_as_uint(f);
  unsigned int r = u + 0x7FFFu + ((u >> 16) & 1u);
  return (unsigned short)(r >> 16);
}
__device__ inline float bf_lo(unsigned int u) { return __uint_as_float(u << 16); }
__device__ inline float bf_hi(unsigned int u) { return __uint_as_float(u & 0xffff0000u); }

// ---------------- CSR build directly from edge_index ----------------
// i64 detection per wave: under int64 layout every odd int32 word is 0; under int32
// layout those words are random node ids (P(all 64 == 0) ~ (2e-5)^64 = never).
__global__ void hist_direct(const int* __restrict__ ei, int* __restrict__ cnt) {
  int e = blockIdx.x * 256 + threadIdx.x;   // grid covers exactly N_EDGES
  int hi = ei[2 * e + 1];
  bool is64 = (__ballot(hi == 0) == 0xFFFFFFFFFFFFFFFFull);
  int d = is64 ? ei[2 * (N_EDGES + e)] : ei[N_EDGES + e];
  atomicAdd(&cnt[d], 1);
}

__global__ void scatter_direct(const int* __restrict__ ei, int* __restrict__ cursor,
                               int* __restrict__ ssrc) {
  int e = blockIdx.x * 256 + threadIdx.x;
  int hi = ei[2 * e + 1];
  bool is64 = (__ballot(hi == 0) == 0xFFFFFFFFFFFFFFFFull);
  int s, d;
  if (is64) { s = ei[2 * e]; d = ei[2 * (N_EDGES + e)]; }
  else      { s = ei[e];     d = ei[N_EDGES + e]; }
  int p = atomicAdd(&cursor[d], 1);
  ssrc[p] = s;
}

// ---------------- hierarchical coalesced scan ----------------
__device__ inline int block_excl_scan_256(int v, int& total) {
  __shared__ int lds[8];
  int lane = threadIdx.x & 63, wid = threadIdx.x >> 6;
  int orig = v;
#pragma unroll
  for (int off = 1; off < 64; off <<= 1) {
    int t = __shfl_up(v, off);
    if (lane >= off) v += t;
  }
  if (lane == 63) lds[wid] = v;
  __syncthreads();
  if (threadIdx.x == 0) {
    int s = 0;
    for (int w = 0; w < 4; ++w) { int t = lds[w]; lds[w] = s; s += t; }
    lds[4] = s;
  }
  __syncthreads();
  total = lds[4];
  return v + lds[wid] - orig;   // exclusive
}

__global__ __launch_bounds__(256) void scan1(const int* __restrict__ cnt,
                                             int* __restrict__ excl,
                                             int* __restrict__ partials) {
  int i = blockIdx.x * 256 + threadIdx.x;
  int v = (i < N_NODES) ? cnt[i] : 0;
  int total;
  int e = block_excl_scan_256(v, total);
  if (i < N_NODES) excl[i] = e;
  if (threadIdx.x == 0) partials[blockIdx.x] = total;
}

__global__ __launch_bounds__(256) void scan2(int* __restrict__ partials, int nb) {
  int i = threadIdx.x;
  int v = (i < nb) ? partials[i] : 0;
  int total;
  int e = block_excl_scan_256(v, total);
  if (i < nb) partials[i] = e;
}

__global__ __launch_bounds__(256) void scan3(int* __restrict__ row_ptr,
                                             const int* __restrict__ partials,
                                             int* __restrict__ cursor) {
  int i = blockIdx.x * 256 + threadIdx.x;
  if (i < N_NODES) {
    int v = row_ptr[i] + partials[blockIdx.x];
    row_ptr[i] = v;
    cursor[i] = v;
  }
  if (i == 0) row_ptr[N_NODES] = N_EDGES;
}

// ---------------- weight prep for BOTH layers in one launch ----------------
// bt_all[lay][col][k] bf16 (transposed weights), bcat_all[lay][col] f32.
struct WPack { const float* W[8]; const float* B[8]; };

__global__ void prep_w_both(WPack pk, unsigned short* __restrict__ bt_all,
                            float* __restrict__ bcat_all) {
  int t = blockIdx.x * 256 + threadIdx.x;  // 131072 threads
  int lay = t >> 16;
  int r = t & 65535;
  int col = r >> 7, kk = r & 127;
  int sel = col >> 7, c = col & 127;
  int idx = lay * 4 + sel;
  const float* W = pk.W[idx];
  bt_all[(size_t)lay * 65536 + col * 128 + kk] = f2bf(W[kk * 128 + c]);
  if (kk == 0) bcat_all[lay * 512 + col] = pk.B[idx][c];
}

// ---------------- GEMM: [50000x128] @ [128x512] ----------------
// wave job: 64-col group x 80 rows (5 x 16-row tiles); B loaded once per wave;
// A-tile for rt+1 prefetched before the MFMAs of rt (depth-2 pipeline).
// colGroup = wid*2 + (block&1): an even block owns cg {0,2,4,6} (q/k/v/s cols 0-63)
// so each 128B line of Okv (k+v interleave) is written by ONE block -> no
// partial-line write amplification (was 1.46x with cg = gw&7).
// Outputs: q (cols 0..127)   -> Oqs bf16 [N][256] first half
//          s (cols 384..511) -> Oqs bf16 [N][256] second half
//          k (128..255), v (256..383) -> Okv bf16 [N][256] interleaved:
//              entry 4t+0=k(2t) 4t+1=k(2t+1) 4t+2=v(2t) 4t+3=v(2t+1)
template <bool AF32>
__device__ inline void load_a(const void* xa, int m0, int r, int half, bf16x8* fr4) {
  if constexpr (AF32) {
    const float* ap = (const float*)xa + (size_t)(m0 + r) * 128 + half * 8;
#pragma unroll
    for (int kc = 0; kc < 4; ++kc) {
      float4 f0 = *(const float4*)(ap + kc * 32);
      float4 f1 = *(const float4*)(ap + kc * 32 + 4);
      bf16x8 fr;
      fr[0] = (short)f2bf(f0.x); fr[1] = (short)f2bf(f0.y);
      fr[2] = (short)f2bf(f0.z); fr[3] = (short)f2bf(f0.w);
      fr[4] = (short)f2bf(f1.x); fr[5] = (short)f2bf(f1.y);
      fr[6] = (short)f2bf(f1.z); fr[7] = (short)f2bf(f1.w);
      fr4[kc] = fr;
    }
  } else {
    const unsigned short* ap = (const unsigned short*)xa + (size_t)(m0 + r) * 128 + half * 8;
#pragma unroll
    for (int kc = 0; kc < 4; ++kc) fr4[kc] = *(const bf16x8*)(ap + kc * 32);
  }
}

template <bool AF32>
__global__ __launch_bounds__(256) void gemm_qkvs(const void* __restrict__ xa,
                                                 const unsigned short* __restrict__ bt,
                                                 const float* __restrict__ bias,
                                                 unsigned short* __restrict__ Oqs,
                                                 unsigned short* __restrict__ Okv) {
  const int wid = threadIdx.x >> 6;
  const int lane = threadIdx.x & 63;
  const int gw = blockIdx.x * 4 + wid;       // 0..4999
  const int colGroup = ((gw & 3) << 1) | ((gw >> 2) & 1);  // wid*2 + block parity
  const int rowGroup = gw >> 3;              // 0..624 (x5 row tiles)
  const int col0 = colGroup * 64;
  const int r = lane & 15;
  const int half = lane >> 4;                // 0..3

  bf16x8 bfrag[4][4];                        // [ct][kc]
#pragma unroll
  for (int ct = 0; ct < 4; ++ct) {
    int col = col0 + ct * 16 + r;
    const unsigned short* bp = bt + col * 128 + half * 8;
#pragma unroll
    for (int kc = 0; kc < 4; ++kc)
      bfrag[ct][kc] = *(const bf16x8*)(bp + kc * 32);
  }

  bf16x8 aN[4];
  load_a<AF32>(xa, rowGroup * 5 * 16, r, half, aN);   // prefetch rt=0

#pragma unroll 1
  for (int rt = 0; rt < 5; ++rt) {
    int m0 = (rowGroup * 5 + rt) * 16;
    bf16x8 afrag[4];
#pragma unroll
    for (int kc = 0; kc < 4; ++kc) afrag[kc] = aN[kc];
    if (rt < 4) load_a<AF32>(xa, m0 + 16, r, half, aN);  // prefetch next tile

    f32x4 acc[4] = {{0.f,0.f,0.f,0.f},{0.f,0.f,0.f,0.f},{0.f,0.f,0.f,0.f},{0.f,0.f,0.f,0.f}};
#pragma unroll
    for (int ct = 0; ct < 4; ++ct)
#pragma unroll
      for (int kc = 0; kc < 4; ++kc)
        acc[ct] = __builtin_amdgcn_mfma_f32_16x16x32_bf16(afrag[kc], bfrag[ct][kc], acc[ct], 0, 0, 0);

    int orow = m0 + half * 4;
    if (colGroup < 2) {            // q -> Oqs[:, col]
#pragma unroll
      for (int ct = 0; ct < 4; ++ct) {
        int col = col0 + ct * 16 + r;
        float bv = bias[col];
#pragma unroll
        for (int j = 0; j < 4; ++j)
          Oqs[(size_t)(orow + j) * 256 + col] = f2bf(acc[ct][j] + bv);
      }
    } else if (colGroup >= 6) {    // s -> Oqs[:, 128 + c]
#pragma unroll
      for (int ct = 0; ct < 4; ++ct) {
        int col = col0 + ct * 16 + r;
        float bv = bias[col];
        int c = col - 384;
#pragma unroll
        for (int j = 0; j < 4; ++j)
          Oqs[(size_t)(orow + j) * 256 + 128 + c] = f2bf(acc[ct][j] + bv);
      }
    } else {                       // k or v -> Okv interleaved
      const int voff  = (colGroup >= 4) ? 2 : 0;
      const int cbase = (colGroup >= 4) ? 256 : 128;
#pragma unroll
      for (int ct = 0; ct < 4; ++ct) {
        int col = col0 + ct * 16 + r;
        float bv = bias[col];
        int c = col - cbase;
        int pos = ((c >> 1) << 2) + voff + (c & 1);
#pragma unroll
        for (int j = 0; j < 4; ++j)
          Okv[(size_t)(orow + j) * 256 + pos] = f2bf(acc[ct][j] + bv);
      }
    }
  }
}

// ---------------- edge attention: one wave per destination node ----------------
// Lane l owns channels 2l, 2l+1. One 8B kv gather per lane per edge, depth-4 pipeline.
template <int H, bool OUTBF>
__global__ __launch_bounds__(256, 8) void edge_attn(const unsigned short* __restrict__ Oqs,
                                                    const unsigned short* __restrict__ Okv,
                                                    const int* __restrict__ row_ptr,
                                                    const int* __restrict__ ssrc,
                                                    void* __restrict__ outp,
                                                    float scale) {
  int wid = threadIdx.x >> 6, lane = threadIdx.x & 63;
  int n = blockIdx.x * 4 + wid;
  if (n >= N_NODES) return;
  const unsigned int* qsw = (const unsigned int*)Oqs;  // node stride: 128 u32
  unsigned int qw = qsw[(size_t)n * 128 + lane];
#if HAVE_FDOT2
  const float esc = scale;              // q stays packed bf16; scale folded into exp arg
  bf16v2 qv = __builtin_bit_cast(bf16v2, qw);
#else
  float qx = bf_lo(qw) * scale, qy = bf_hi(qw) * scale;
#endif
  int start = row_ptr[n], end = row_ptr[n + 1];
  int len = end - start;
  const int* sp = ssrc + start;
  const uint2* kvb = (const uint2*)Okv;  // node stride: 64 uint2
  float acc0 = 0.f, acc1 = 0.f, den = 0.f;

  auto proc = [&](uint2 kv) {
#if HAVE_FDOT2
    float p = __builtin_amdgcn_fdot2_f32_bf16(__builtin_bit_cast(bf16v2, kv.x), qv, 0.f, false);
#else
    float p = qx * bf_lo(kv.x) + qy * bf_hi(kv.x);
#endif
#pragma unroll
    for (int off = 1; off < 64 / H; off <<= 1) p += __shfl_xor(p, off);
#if HAVE_FDOT2
    float e = __expf(p * esc);
#else
    float e = __expf(p);
#endif
    den += e; acc0 += e * bf_lo(kv.y); acc1 += e * bf_hi(kv.y);
  };

  int i = 0;
  if (len >= 4) {
    uint2 a = kvb[(size_t)sp[0] * 64 + lane];
    uint2 b = kvb[(size_t)sp[1] * 64 + lane];
    uint2 c = kvb[(size_t)sp[2] * 64 + lane];
    uint2 d = kvb[(size_t)sp[3] * 64 + lane];
    for (i = 4; i + 3 < len; i += 4) {
      uint2 na = kvb[(size_t)sp[i]     * 64 + lane];
      uint2 nb = kvb[(size_t)sp[i + 1] * 64 + lane];
      uint2 nc = kvb[(size_t)sp[i + 2] * 64 + lane];
      uint2 nd = kvb[(size_t)sp[i + 3] * 64 + lane];
      proc(a); proc(b); proc(c); proc(d);
      a = na; b = nb; c = nc; d = nd;
    }
    proc(a); proc(b); proc(c); proc(d);
  }
  for (; i < len; ++i) proc(kvb[(size_t)sp[i] * 64 + lane]);

  float inv = 1.0f / (den + 1e-16f);
  unsigned int sw = qsw[(size_t)n * 128 + 64 + lane];
  float r0 = acc0 * inv + bf_lo(sw);
  float r1 = acc1 * inv + bf_hi(sw);
  if (OUTBF) {  // layer 1: relu + pack bf16 directly for layer-2 GEMM input
    r0 = fmaxf(r0, 0.f); r1 = fmaxf(r1, 0.f);
    unsigned int pkv = (unsigned int)f2bf(r0) | ((unsigned int)f2bf(r1) << 16);
    ((unsigned int*)outp)[(size_t)n * 64 + lane] = pkv;
  } else {
    ((float2*)outp)[(size_t)n * 64 + lane] = make_float2(r0, r1);
  }
}

// ---------------- launch ----------------
extern "C" void kernel_launch(void* const* d_in, const int* in_sizes, int n_in,
                              void* d_out, int out_size, void* d_ws, size_t ws_size,
                              hipStream_t stream) {
  (void)in_sizes; (void)n_in; (void)out_size; (void)ws_size;
  const float* x  = (const float*)d_in[0];
  const int*   ei = (const int*)d_in[1];
  float* out = (float*)d_out;

  char* w = (char*)d_ws;
  size_t off = 0;
  auto alloc = [&](size_t b) { void* p = w + off; off += (b + 255) & ~(size_t)255; return p; };
  int* ssrc   = (int*)alloc((size_t)N_EDGES * 4);
  int* rowp   = (int*)alloc((size_t)(N_NODES + 1) * 4);
  int* cursor = (int*)alloc((size_t)N_NODES * 4);
  int* cnt    = (int*)alloc((size_t)N_NODES * 4);
  int* part   = (int*)alloc(256 * 4);
  unsigned short* xb  = (unsigned short*)alloc((size_t)N_NODES * 128 * 2);
  unsigned short* bt  = (unsigned short*)alloc((size_t)2 * 512 * 128 * 2);
  float* bcat = (float*)alloc(2 * 512 * 4);
  unsigned short* Oqs = (unsigned short*)alloc((size_t)N_NODES * 256 * 2);
  unsigned short* Okv = (unsigned short*)alloc((size_t)N_NODES * 256 * 2);

  WPack pk;
  for (int i = 0; i < 8; ++i) { pk.W[i] = (const float*)d_in[2 + 2 * i]; pk.B[i] = (const float*)d_in[3 + 2 * i]; }

  hipMemsetAsync(cnt, 0, (size_t)N_NODES * 4, stream);
  hist_direct<<<3125, 256, 0, stream>>>(ei, cnt);
  scan1<<<196, 256, 0, stream>>>(cnt, rowp, part);
  scan2<<<1, 256, 0, stream>>>(part, 196);
  scan3<<<196, 256, 0, stream>>>(rowp, part, cursor);
  scatter_direct<<<3125, 256, 0, stream>>>(ei, cursor, ssrc);
  prep_w_both<<<512, 256, 0, stream>>>(pk, bt, bcat);

  // ---- layer 1 (H=4, d=32) ----
  gemm_qkvs<true><<<1250, 256, 0, stream>>>(x, bt, bcat, Oqs, Okv);
  edge_attn<4, true><<<12500, 256, 0, stream>>>(Oqs, Okv, rowp, ssrc, xb, 0.17677669529663689f);

  // ---- layer 2 (H=1, d=128) ----
  gemm_qkvs<false><<<1250, 256, 0, stream>>>(xb, bt + 65536, bcat + 512, Oqs, Okv);
  edge_attn<1, false><<<12500, 256, 0, stream>>>(Oqs, Okv, rowp, ssrc, out, 0.08838834764831845f);
}

// Round 14
// 387.854 us; speedup vs baseline: 2.3923x; 1.0168x over previous
//
#include <hip/hip_runtime.h>

#define N_NODES 50000
#define N_EDGES 800000

typedef __attribute__((ext_vector_type(8))) short bf16x8;
typedef __attribute__((ext_vector_type(4))) float f32x4;

#if __has_builtin(__builtin_amdgcn_fdot2_f32_bf16)
#define HAVE_FDOT2 1
typedef __attribute__((ext_vector_type(2))) __bf16 bf16v2;
#else
#define HAVE_FDOT2 0
#endif

__device__ inline unsigned short f2bf(float f) {
  unsigned int u = __float_as_uint(f);
  unsigned int r = u + 0x7FFFu + ((u >> 16) & 1u);
  return (unsigned short)(r >> 16);
}
__device__ inline float bf_lo(unsigned int u) { return __uint_as_float(u << 16); }
__device__ inline float bf_hi(unsigned int u) { return __uint_as_float(u & 0xffff0000u); }

// ---------------- CSR build directly from edge_index ----------------
__global__ void hist_direct(const int* __restrict__ ei, int* __restrict__ cnt) {
  int e = blockIdx.x * 256 + threadIdx.x;   // grid covers exactly N_EDGES
  int hi = ei[2 * e + 1];
  bool is64 = (__ballot(hi == 0) == 0xFFFFFFFFFFFFFFFFull);
  int d = is64 ? ei[2 * (N_EDGES + e)] : ei[N_EDGES + e];
  atomicAdd(&cnt[d], 1);
}

__global__ void scatter_direct(const int* __restrict__ ei, int* __restrict__ cursor,
                               int* __restrict__ ssrc) {
  int e = blockIdx.x * 256 + threadIdx.x;
  int hi = ei[2 * e + 1];
  bool is64 = (__ballot(hi == 0) == 0xFFFFFFFFFFFFFFFFull);
  int s, d;
  if (is64) { s = ei[2 * e]; d = ei[2 * (N_EDGES + e)]; }
  else      { s = ei[e];     d = ei[N_EDGES + e]; }
  int p = atomicAdd(&cursor[d], 1);
  ssrc[p] = s;
}

// ---------------- hierarchical coalesced scan ----------------
__device__ inline int block_excl_scan_256(int v, int& total) {
  __shared__ int lds[8];
  int lane = threadIdx.x & 63, wid = threadIdx.x >> 6;
  int orig = v;
#pragma unroll
  for (int off = 1; off < 64; off <<= 1) {
    int t = __shfl_up(v, off);
    if (lane >= off) v += t;
  }
  if (lane == 63) lds[wid] = v;
  __syncthreads();
  if (threadIdx.x == 0) {
    int s = 0;
    for (int w = 0; w < 4; ++w) { int t = lds[w]; lds[w] = s; s += t; }
    lds[4] = s;
  }
  __syncthreads();
  total = lds[4];
  return v + lds[wid] - orig;   // exclusive
}

__global__ __launch_bounds__(256) void scan1(const int* __restrict__ cnt,
                                             int* __restrict__ excl,
                                             int* __restrict__ partials) {
  int i = blockIdx.x * 256 + threadIdx.x;
  int v = (i < N_NODES) ? cnt[i] : 0;
  int total;
  int e = block_excl_scan_256(v, total);
  if (i < N_NODES) excl[i] = e;
  if (threadIdx.x == 0) partials[blockIdx.x] = total;
}

__global__ __launch_bounds__(256) void scan2(int* __restrict__ partials, int nb) {
  int i = threadIdx.x;
  int v = (i < nb) ? partials[i] : 0;
  int total;
  int e = block_excl_scan_256(v, total);
  if (i < nb) partials[i] = e;
}

__global__ __launch_bounds__(256) void scan3(int* __restrict__ row_ptr,
                                             const int* __restrict__ partials,
                                             int* __restrict__ cursor) {
  int i = blockIdx.x * 256 + threadIdx.x;
  if (i < N_NODES) {
    int v = row_ptr[i] + partials[blockIdx.x];
    row_ptr[i] = v;
    cursor[i] = v;
  }
  if (i == 0) row_ptr[N_NODES] = N_EDGES;
}

// ---------------- weight prep for BOTH layers in one launch ----------------
struct WPack { const float* W[8]; const float* B[8]; };

__global__ void prep_w_both(WPack pk, unsigned short* __restrict__ bt_all,
                            float* __restrict__ bcat_all) {
  int t = blockIdx.x * 256 + threadIdx.x;  // 131072 threads
  int lay = t >> 16;
  int r = t & 65535;
  int col = r >> 7, kk = r & 127;
  int sel = col >> 7, c = col & 127;
  int idx = lay * 4 + sel;
  const float* W = pk.W[idx];
  bt_all[(size_t)lay * 65536 + col * 128 + kk] = f2bf(W[kk * 128 + c]);
  if (kk == 0) bcat_all[lay * 512 + col] = pk.B[idx][c];
}

// ---------------- GEMM: [50000x128] @ [128x512] ----------------
// Block = 4 waves {q,k,v,s} of one 64-col half (parity = blockIdx&1) over 80 rows
// (rowGroup = blockIdx>>1, 5 x 16-row tiles). B loaded once/wave; A prefetched
// depth-2. Epilogue: all 4 waves repack bf16 results into a shared 16x528B LDS
// image (final interleaved layout), then 256 threads store contiguous 32B each
// (fully coalesced 128B lines) -> replaces 16 scattered 2B stores/lane/tile.
// Outputs: Oqs bf16 [N][256] = q(0:128)|s(128:256); Okv bf16 [N][256] interleaved
//          4t+0=k(2t) 4t+1=k(2t+1) 4t+2=v(2t) 4t+3=v(2t+1).
template <bool AF32>
__device__ inline void load_a(const void* xa, int m0, int r, int half, bf16x8* fr4) {
  if constexpr (AF32) {
    const float* ap = (const float*)xa + (size_t)(m0 + r) * 128 + half * 8;
#pragma unroll
    for (int kc = 0; kc < 4; ++kc) {
      float4 f0 = *(const float4*)(ap + kc * 32);
      float4 f1 = *(const float4*)(ap + kc * 32 + 4);
      bf16x8 fr;
      fr[0] = (short)f2bf(f0.x); fr[1] = (short)f2bf(f0.y);
      fr[2] = (short)f2bf(f0.z); fr[3] = (short)f2bf(f0.w);
      fr[4] = (short)f2bf(f1.x); fr[5] = (short)f2bf(f1.y);
      fr[6] = (short)f2bf(f1.z); fr[7] = (short)f2bf(f1.w);
      fr4[kc] = fr;
    }
  } else {
    const unsigned short* ap = (const unsigned short*)xa + (size_t)(m0 + r) * 128 + half * 8;
#pragma unroll
    for (int kc = 0; kc < 4; ++kc) fr4[kc] = *(const bf16x8*)(ap + kc * 32);
  }
}

#define IMG_STRIDE 264   // ushorts per LDS image row (512B payload + 16B pad)

template <bool AF32>
__global__ __launch_bounds__(256) void gemm_qkvs(const void* __restrict__ xa,
                                                 const unsigned short* __restrict__ bt,
                                                 const float* __restrict__ bias,
                                                 unsigned short* __restrict__ Oqs,
                                                 unsigned short* __restrict__ Okv) {
  __shared__ unsigned short img[16 * IMG_STRIDE];
  const int wid = threadIdx.x >> 6;          // 0=q 1=k 2=v 3=s
  const int lane = threadIdx.x & 63;
  const int parity = blockIdx.x & 1;         // which 64-col half
  const int rowGroup = blockIdx.x >> 1;      // 0..624
  const int cg = wid * 2 + parity;           // original colGroup 0..7
  const int col0 = cg * 64;
  const int r = lane & 15;
  const int half = lane >> 4;                // 0..3

  bf16x8 bfrag[4][4];                        // [ct][kc]
#pragma unroll
  for (int ct = 0; ct < 4; ++ct) {
    int col = col0 + ct * 16 + r;
    const unsigned short* bp = bt + col * 128 + half * 8;
#pragma unroll
    for (int kc = 0; kc < 4; ++kc)
      bfrag[ct][kc] = *(const bf16x8*)(bp + kc * 32);
  }

  // LDS image ushort index for this wave's column c_local = ct*16 + r:
  //  q: cl            k: 64 + 4*(cl>>1) + (cl&1)
  //  v: 64 + 4*(cl>>1) + 2 + (cl&1)      s: 192 + cl
  int imgidx[4];
  float bcol[4];
#pragma unroll
  for (int ct = 0; ct < 4; ++ct) {
    int cl = ct * 16 + r;
    int ix;
    if (wid == 0)      ix = cl;
    else if (wid == 1) ix = 64 + ((cl >> 1) << 2) + (cl & 1);
    else if (wid == 2) ix = 64 + ((cl >> 1) << 2) + 2 + (cl & 1);
    else               ix = 192 + cl;
    imgidx[ct] = ix;
    bcol[ct] = bias[col0 + cl];
  }

  bf16x8 aN[4];
  load_a<AF32>(xa, rowGroup * 5 * 16, r, half, aN);   // prefetch rt=0

#pragma unroll 1
  for (int rt = 0; rt < 5; ++rt) {
    int m0 = (rowGroup * 5 + rt) * 16;
    bf16x8 afrag[4];
#pragma unroll
    for (int kc = 0; kc < 4; ++kc) afrag[kc] = aN[kc];
    if (rt < 4) load_a<AF32>(xa, m0 + 16, r, half, aN);  // prefetch next tile

    f32x4 acc[4] = {{0.f,0.f,0.f,0.f},{0.f,0.f,0.f,0.f},{0.f,0.f,0.f,0.f},{0.f,0.f,0.f,0.f}};
#pragma unroll
    for (int ct = 0; ct < 4; ++ct)
#pragma unroll
      for (int kc = 0; kc < 4; ++kc)
        acc[ct] = __builtin_amdgcn_mfma_f32_16x16x32_bf16(afrag[kc], bfrag[ct][kc], acc[ct], 0, 0, 0);

    // repack into shared image (rows = half*4+j)
#pragma unroll
    for (int ct = 0; ct < 4; ++ct)
#pragma unroll
      for (int j = 0; j < 4; ++j)
        img[(half * 4 + j) * IMG_STRIDE + imgidx[ct]] = f2bf(acc[ct][j] + bcol[ct]);
    __syncthreads();

    // cooperative coalesced store: thread t -> (row = t>>4, 32B chunk = t&15)
    {
      int t = threadIdx.x;
      int row = t >> 4, c = t & 15;
      const uint4* lp = (const uint4*)(img + row * IMG_STRIDE + c * 16);
      uint4 v0 = lp[0], v1 = lp[1];
      int grow = (m0 + row) * 256;
      unsigned short* g;
      if (c < 4)       g = Oqs + grow + parity * 64 + c * 16;
      else if (c < 12) g = Okv + grow + parity * 128 + (c * 16 - 64);
      else             g = Oqs + grow + 128 + parity * 64 + (c * 16 - 192);
      *(uint4*)g = v0;
      *(uint4*)(g + 8) = v1;
    }
    __syncthreads();
  }
}

// ---------------- edge attention: one wave per destination node ----------------
// Lane l owns channels 2l, 2l+1. One 8B kv gather per lane per edge, depth-4 pipeline.
template <int H, bool OUTBF>
__global__ __launch_bounds__(256, 8) void edge_attn(const unsigned short* __restrict__ Oqs,
                                                    const unsigned short* __restrict__ Okv,
                                                    const int* __restrict__ row_ptr,
                                                    const int* __restrict__ ssrc,
                                                    void* __restrict__ outp,
                                                    float scale) {
  int wid = threadIdx.x >> 6, lane = threadIdx.x & 63;
  int n = blockIdx.x * 4 + wid;
  if (n >= N_NODES) return;
  const unsigned int* qsw = (const unsigned int*)Oqs;  // node stride: 128 u32
  unsigned int qw = qsw[(size_t)n * 128 + lane];
#if HAVE_FDOT2
  const float esc = scale;              // q stays packed bf16; scale folded into exp arg
  bf16v2 qv = __builtin_bit_cast(bf16v2, qw);
#else
  float qx = bf_lo(qw) * scale, qy = bf_hi(qw) * scale;
#endif
  int start = row_ptr[n], end = row_ptr[n + 1];
  int len = end - start;
  const int* sp = ssrc + start;
  const uint2* kvb = (const uint2*)Okv;  // node stride: 64 uint2
  float acc0 = 0.f, acc1 = 0.f, den = 0.f;

  auto proc = [&](uint2 kv) {
#if HAVE_FDOT2
    float p = __builtin_amdgcn_fdot2_f32_bf16(__builtin_bit_cast(bf16v2, kv.x), qv, 0.f, false);
#else
    float p = qx * bf_lo(kv.x) + qy * bf_hi(kv.x);
#endif
#pragma unroll
    for (int off = 1; off < 64 / H; off <<= 1) p += __shfl_xor(p, off);
#if HAVE_FDOT2
    float e = __expf(p * esc);
#else
    float e = __expf(p);
#endif
    den += e; acc0 += e * bf_lo(kv.y); acc1 += e * bf_hi(kv.y);
  };

  int i = 0;
  if (len >= 4) {
    uint2 a = kvb[(size_t)sp[0] * 64 + lane];
    uint2 b = kvb[(size_t)sp[1] * 64 + lane];
    uint2 c = kvb[(size_t)sp[2] * 64 + lane];
    uint2 d = kvb[(size_t)sp[3] * 64 + lane];
    for (i = 4; i + 3 < len; i += 4) {
      uint2 na = kvb[(size_t)sp[i]     * 64 + lane];
      uint2 nb = kvb[(size_t)sp[i + 1] * 64 + lane];
      uint2 nc = kvb[(size_t)sp[i + 2] * 64 + lane];
      uint2 nd = kvb[(size_t)sp[i + 3] * 64 + lane];
      proc(a); proc(b); proc(c); proc(d);
      a = na; b = nb; c = nc; d = nd;
    }
    proc(a); proc(b); proc(c); proc(d);
  }
  for (; i < len; ++i) proc(kvb[(size_t)sp[i] * 64 + lane]);

  float inv = 1.0f / (den + 1e-16f);
  unsigned int sw = qsw[(size_t)n * 128 + 64 + lane];
  float r0 = acc0 * inv + bf_lo(sw);
  float r1 = acc1 * inv + bf_hi(sw);
  if (OUTBF) {  // layer 1: relu + pack bf16 directly for layer-2 GEMM input
    r0 = fmaxf(r0, 0.f); r1 = fmaxf(r1, 0.f);
    unsigned int pkv = (unsigned int)f2bf(r0) | ((unsigned int)f2bf(r1) << 16);
    ((unsigned int*)outp)[(size_t)n * 64 + lane] = pkv;
  } else {
    ((float2*)outp)[(size_t)n * 64 + lane] = make_float2(r0, r1);
  }
}

// ---------------- launch ----------------
extern "C" void kernel_launch(void* const* d_in, const int* in_sizes, int n_in,
                              void* d_out, int out_size, void* d_ws, size_t ws_size,
                              hipStream_t stream) {
  (void)in_sizes; (void)n_in; (void)out_size; (void)ws_size;
  const float* x  = (const float*)d_in[0];
  const int*   ei = (const int*)d_in[1];
  float* out = (float*)d_out;

  char* w = (char*)d_ws;
  size_t off = 0;
  auto alloc = [&](size_t b) { void* p = w + off; off += (b + 255) & ~(size_t)255; return p; };
  int* ssrc   = (int*)alloc((size_t)N_EDGES * 4);
  int* rowp   = (int*)alloc((size_t)(N_NODES + 1) * 4);
  int* cursor = (int*)alloc((size_t)N_NODES * 4);
  int* cnt    = (int*)alloc((size_t)N_NODES * 4);
  int* part   = (int*)alloc(256 * 4);
  unsigned short* xb  = (unsigned short*)alloc((size_t)N_NODES * 128 * 2);
  unsigned short* bt  = (unsigned short*)alloc((size_t)2 * 512 * 128 * 2);
  float* bcat = (float*)alloc(2 * 512 * 4);
  unsigned short* Oqs = (unsigned short*)alloc((size_t)N_NODES * 256 * 2);
  unsigned short* Okv = (unsigned short*)alloc((size_t)N_NODES * 256 * 2);

  WPack pk;
  for (int i = 0; i < 8; ++i) { pk.W[i] = (const float*)d_in[2 + 2 * i]; pk.B[i] = (const float*)d_in[3 + 2 * i]; }

  hipMemsetAsync(cnt, 0, (size_t)N_NODES * 4, stream);
  hist_direct<<<3125, 256, 0, stream>>>(ei, cnt);
  scan1<<<196, 256, 0, stream>>>(cnt, rowp, part);
  scan2<<<1, 256, 0, stream>>>(part, 196);
  scan3<<<196, 256, 0, stream>>>(rowp, part, cursor);
  scatter_direct<<<3125, 256, 0, stream>>>(ei, cursor, ssrc);
  prep_w_both<<<512, 256, 0, stream>>>(pk, bt, bcat);

  // ---- layer 1 (H=4, d=32) ----
  gemm_qkvs<true><<<1250, 256, 0, stream>>>(x, bt, bcat, Oqs, Okv);
  edge_attn<4, true><<<12500, 256, 0, stream>>>(Oqs, Okv, rowp, ssrc, xb, 0.17677669529663689f);

  // ---- layer 2 (H=1, d=128) ----
  gemm_qkvs<false><<<1250, 256, 0, stream>>>(xb, bt + 65536, bcat + 512, Oqs, Okv);
  edge_attn<1, false><<<12500, 256, 0, stream>>>(Oqs, Okv, rowp, ssrc, out, 0.08838834764831845f);
}

// Round 15
// 376.913 us; speedup vs baseline: 2.4617x; 1.0290x over previous
//
#include <hip/hip_runtime.h>

#define N_NODES 50000
#define N_EDGES 800000

typedef __attribute__((ext_vector_type(8))) short bf16x8;
typedef __attribute__((ext_vector_type(4))) float f32x4;

#if __has_builtin(__builtin_amdgcn_fdot2_f32_bf16)
#define HAVE_FDOT2 1
typedef __attribute__((ext_vector_type(2))) __bf16 bf16v2;
#else
#define HAVE_FDOT2 0
#endif

__device__ inline unsigned short f2bf(float f) {
  unsigned int u = __float_as_uint(f);
  unsigned int r = u + 0x7FFFu + ((u >> 16) & 1u);
  return (unsigned short)(r >> 16);
}
__device__ inline float bf_lo(unsigned int u) { return __uint_as_float(u << 16); }
__device__ inline float bf_hi(unsigned int u) { return __uint_as_float(u & 0xffff0000u); }

struct WPack { const float* W[8]; const float* B[8]; };

// ---------------- hierarchical coalesced scan ----------------
__device__ inline int block_excl_scan_256(int v, int& total) {
  __shared__ int lds[8];
  int lane = threadIdx.x & 63, wid = threadIdx.x >> 6;
  int orig = v;
#pragma unroll
  for (int off = 1; off < 64; off <<= 1) {
    int t = __shfl_up(v, off);
    if (lane >= off) v += t;
  }
  if (lane == 63) lds[wid] = v;
  __syncthreads();
  if (threadIdx.x == 0) {
    int s = 0;
    for (int w = 0; w < 4; ++w) { int t = lds[w]; lds[w] = s; s += t; }
    lds[4] = s;
  }
  __syncthreads();
  total = lds[4];
  return v + lds[wid] - orig;   // exclusive
}

__global__ __launch_bounds__(256) void scan1(const int* __restrict__ cnt,
                                             int* __restrict__ excl,
                                             int* __restrict__ partials) {
  int i = blockIdx.x * 256 + threadIdx.x;
  int v = (i < N_NODES) ? cnt[i] : 0;
  int total;
  int e = block_excl_scan_256(v, total);
  if (i < N_NODES) excl[i] = e;
  if (threadIdx.x == 0) partials[blockIdx.x] = total;
}

__global__ __launch_bounds__(256) void scan2(int* __restrict__ partials, int nb) {
  int i = threadIdx.x;
  int v = (i < nb) ? partials[i] : 0;
  int total;
  int e = block_excl_scan_256(v, total);
  if (i < nb) partials[i] = e;
}

__global__ __launch_bounds__(256) void scan3(int* __restrict__ row_ptr,
                                             const int* __restrict__ partials,
                                             int* __restrict__ cursor) {
  int i = blockIdx.x * 256 + threadIdx.x;
  if (i < N_NODES) {
    int v = row_ptr[i] + partials[blockIdx.x];
    row_ptr[i] = v;
    cursor[i] = v;
  }
  if (i == 0) row_ptr[N_NODES] = N_EDGES;
}

// ---------------- fused: histogram (blocks 0..3124) || weight prep (3125..3636) ----------------
__global__ __launch_bounds__(256) void hist_prep(const int* __restrict__ ei,
                                                 int* __restrict__ cnt,
                                                 WPack pk,
                                                 unsigned short* __restrict__ bt_all,
                                                 float* __restrict__ bcat_all) {
  if (blockIdx.x < 3125) {
    int e = blockIdx.x * 256 + threadIdx.x;   // covers exactly N_EDGES
    int hi = ei[2 * e + 1];
    bool is64 = (__ballot(hi == 0) == 0xFFFFFFFFFFFFFFFFull);
    int d = is64 ? ei[2 * (N_EDGES + e)] : ei[N_EDGES + e];
    atomicAdd(&cnt[d], 1);
  } else {
    int t = (blockIdx.x - 3125) * 256 + threadIdx.x;  // 131072 threads
    int lay = t >> 16;
    int r = t & 65535;
    int col = r >> 7, kk = r & 127;
    int sel = col >> 7, c = col & 127;
    int idx = lay * 4 + sel;
    bt_all[(size_t)lay * 65536 + col * 128 + kk] = f2bf(pk.W[idx][kk * 128 + c]);
    if (kk == 0) bcat_all[lay * 512 + col] = pk.B[idx][c];
  }
}

// ---------------- GEMM body (shared by standalone + fused kernels) ----------------
// Block = 4 waves {q,k,v,s} of one 64-col half (parity = bid&1) over 80 rows
// (rowGroup = bid>>1, 5 x 16-row tiles). B loaded once/wave; A prefetched depth-2.
// Epilogue: repack into 16x528B LDS image, cooperative 32B/thread coalesced store.
// Outputs: Oqs bf16 [N][256] = q(0:128)|s(128:256); Okv bf16 [N][256] interleaved
//          4t+0=k(2t) 4t+1=k(2t+1) 4t+2=v(2t) 4t+3=v(2t+1).
template <bool AF32>
__device__ inline void load_a(const void* xa, int m0, int r, int half, bf16x8* fr4) {
  if constexpr (AF32) {
    const float* ap = (const float*)xa + (size_t)(m0 + r) * 128 + half * 8;
#pragma unroll
    for (int kc = 0; kc < 4; ++kc) {
      float4 f0 = *(const float4*)(ap + kc * 32);
      float4 f1 = *(const float4*)(ap + kc * 32 + 4);
      bf16x8 fr;
      fr[0] = (short)f2bf(f0.x); fr[1] = (short)f2bf(f0.y);
      fr[2] = (short)f2bf(f0.z); fr[3] = (short)f2bf(f0.w);
      fr[4] = (short)f2bf(f1.x); fr[5] = (short)f2bf(f1.y);
      fr[6] = (short)f2bf(f1.z); fr[7] = (short)f2bf(f1.w);
      fr4[kc] = fr;
    }
  } else {
    const unsigned short* ap = (const unsigned short*)xa + (size_t)(m0 + r) * 128 + half * 8;
#pragma unroll
    for (int kc = 0; kc < 4; ++kc) fr4[kc] = *(const bf16x8*)(ap + kc * 32);
  }
}

#define IMG_STRIDE 264   // ushorts per LDS image row (512B payload + 16B pad)

template <bool AF32>
__device__ inline void gemm_body(int bid, const void* __restrict__ xa,
                                 const unsigned short* __restrict__ bt,
                                 const float* __restrict__ bias,
                                 unsigned short* __restrict__ Oqs,
                                 unsigned short* __restrict__ Okv,
                                 unsigned short* img) {
  const int wid = threadIdx.x >> 6;          // 0=q 1=k 2=v 3=s
  const int lane = threadIdx.x & 63;
  const int parity = bid & 1;                // which 64-col half
  const int rowGroup = bid >> 1;             // 0..624
  const int cg = wid * 2 + parity;           // original colGroup 0..7
  const int col0 = cg * 64;
  const int r = lane & 15;
  const int half = lane >> 4;                // 0..3

  bf16x8 bfrag[4][4];                        // [ct][kc]
#pragma unroll
  for (int ct = 0; ct < 4; ++ct) {
    int col = col0 + ct * 16 + r;
    const unsigned short* bp = bt + col * 128 + half * 8;
#pragma unroll
    for (int kc = 0; kc < 4; ++kc)
      bfrag[ct][kc] = *(const bf16x8*)(bp + kc * 32);
  }

  // LDS image ushort index for this wave's column cl = ct*16 + r:
  //  q: cl   k: 64+4*(cl>>1)+(cl&1)   v: 64+4*(cl>>1)+2+(cl&1)   s: 192+cl
  int imgidx[4];
  float bcol[4];
#pragma unroll
  for (int ct = 0; ct < 4; ++ct) {
    int cl = ct * 16 + r;
    int ix;
    if (wid == 0)      ix = cl;
    else if (wid == 1) ix = 64 + ((cl >> 1) << 2) + (cl & 1);
    else if (wid == 2) ix = 64 + ((cl >> 1) << 2) + 2 + (cl & 1);
    else               ix = 192 + cl;
    imgidx[ct] = ix;
    bcol[ct] = bias[col0 + cl];
  }

  bf16x8 aN[4];
  load_a<AF32>(xa, rowGroup * 5 * 16, r, half, aN);   // prefetch rt=0

#pragma unroll 1
  for (int rt = 0; rt < 5; ++rt) {
    int m0 = (rowGroup * 5 + rt) * 16;
    bf16x8 afrag[4];
#pragma unroll
    for (int kc = 0; kc < 4; ++kc) afrag[kc] = aN[kc];
    if (rt < 4) load_a<AF32>(xa, m0 + 16, r, half, aN);  // prefetch next tile

    f32x4 acc[4] = {{0.f,0.f,0.f,0.f},{0.f,0.f,0.f,0.f},{0.f,0.f,0.f,0.f},{0.f,0.f,0.f,0.f}};
#pragma unroll
    for (int ct = 0; ct < 4; ++ct)
#pragma unroll
      for (int kc = 0; kc < 4; ++kc)
        acc[ct] = __builtin_amdgcn_mfma_f32_16x16x32_bf16(afrag[kc], bfrag[ct][kc], acc[ct], 0, 0, 0);

    // repack into shared image (rows = half*4+j)
#pragma unroll
    for (int ct = 0; ct < 4; ++ct)
#pragma unroll
      for (int j = 0; j < 4; ++j)
        img[(half * 4 + j) * IMG_STRIDE + imgidx[ct]] = f2bf(acc[ct][j] + bcol[ct]);
    __syncthreads();

    // cooperative coalesced store: thread t -> (row = t>>4, 32B chunk = t&15)
    {
      int t = threadIdx.x;
      int row = t >> 4, c = t & 15;
      const uint4* lp = (const uint4*)(img + row * IMG_STRIDE + c * 16);
      uint4 v0 = lp[0], v1 = lp[1];
      int grow = (m0 + row) * 256;
      unsigned short* g;
      if (c < 4)       g = Oqs + grow + parity * 64 + c * 16;
      else if (c < 12) g = Okv + grow + parity * 128 + (c * 16 - 64);
      else             g = Oqs + grow + 128 + parity * 64 + (c * 16 - 192);
      *(uint4*)g = v0;
      *(uint4*)(g + 8) = v1;
    }
    __syncthreads();
  }
}

// standalone layer-2 GEMM
__global__ __launch_bounds__(256) void gemm_qkvs_bf(const unsigned short* __restrict__ xa,
                                                    const unsigned short* __restrict__ bt,
                                                    const float* __restrict__ bias,
                                                    unsigned short* __restrict__ Oqs,
                                                    unsigned short* __restrict__ Okv) {
  __shared__ unsigned short img[16 * IMG_STRIDE];
  gemm_body<false>(blockIdx.x, xa, bt, bias, Oqs, Okv, img);
}

// fused: layer-1 gemm (blocks 0..1249) || CSR scatter (blocks 1250..4374)
__global__ __launch_bounds__(256) void gemm1_scatter(const float* __restrict__ x,
                                                     const unsigned short* __restrict__ bt,
                                                     const float* __restrict__ bias,
                                                     unsigned short* __restrict__ Oqs,
                                                     unsigned short* __restrict__ Okv,
                                                     const int* __restrict__ ei,
                                                     int* __restrict__ cursor,
                                                     int* __restrict__ ssrc) {
  __shared__ unsigned short img[16 * IMG_STRIDE];
  if (blockIdx.x < 1250) {
    gemm_body<true>(blockIdx.x, x, bt, bias, Oqs, Okv, img);
  } else {
    int e = (blockIdx.x - 1250) * 256 + threadIdx.x;  // covers exactly N_EDGES
    int hi = ei[2 * e + 1];
    bool is64 = (__ballot(hi == 0) == 0xFFFFFFFFFFFFFFFFull);
    int s, d;
    if (is64) { s = ei[2 * e]; d = ei[2 * (N_EDGES + e)]; }
    else      { s = ei[e];     d = ei[N_EDGES + e]; }
    int p = atomicAdd(&cursor[d], 1);
    ssrc[p] = s;
  }
}

// ---------------- edge attention: one wave per destination node ----------------
// Lane l owns channels 2l, 2l+1. One 8B kv gather per lane per edge, depth-4 pipeline.
template <int H, bool OUTBF>
__global__ __launch_bounds__(256, 8) void edge_attn(const unsigned short* __restrict__ Oqs,
                                                    const unsigned short* __restrict__ Okv,
                                                    const int* __restrict__ row_ptr,
                                                    const int* __restrict__ ssrc,
                                                    void* __restrict__ outp,
                                                    float scale) {
  int wid = threadIdx.x >> 6, lane = threadIdx.x & 63;
  int n = blockIdx.x * 4 + wid;
  if (n >= N_NODES) return;
  const unsigned int* qsw = (const unsigned int*)Oqs;  // node stride: 128 u32
  unsigned int qw = qsw[(size_t)n * 128 + lane];
#if HAVE_FDOT2
  const float esc = scale;              // q stays packed bf16; scale folded into exp arg
  bf16v2 qv = __builtin_bit_cast(bf16v2, qw);
#else
  float qx = bf_lo(qw) * scale, qy = bf_hi(qw) * scale;
#endif
  int start = row_ptr[n], end = row_ptr[n + 1];
  int len = end - start;
  const int* sp = ssrc + start;
  const uint2* kvb = (const uint2*)Okv;  // node stride: 64 uint2
  float acc0 = 0.f, acc1 = 0.f, den = 0.f;

  auto proc = [&](uint2 kv) {
#if HAVE_FDOT2
    float p = __builtin_amdgcn_fdot2_f32_bf16(__builtin_bit_cast(bf16v2, kv.x), qv, 0.f, false);
#else
    float p = qx * bf_lo(kv.x) + qy * bf_hi(kv.x);
#endif
#pragma unroll
    for (int off = 1; off < 64 / H; off <<= 1) p += __shfl_xor(p, off);
#if HAVE_FDOT2
    float e = __expf(p * esc);
#else
    float e = __expf(p);
#endif
    den += e; acc0 += e * bf_lo(kv.y); acc1 += e * bf_hi(kv.y);
  };

  int i = 0;
  if (len >= 4) {
    uint2 a = kvb[(size_t)sp[0] * 64 + lane];
    uint2 b = kvb[(size_t)sp[1] * 64 + lane];
    uint2 c = kvb[(size_t)sp[2] * 64 + lane];
    uint2 d = kvb[(size_t)sp[3] * 64 + lane];
    for (i = 4; i + 3 < len; i += 4) {
      uint2 na = kvb[(size_t)sp[i]     * 64 + lane];
      uint2 nb = kvb[(size_t)sp[i + 1] * 64 + lane];
      uint2 nc = kvb[(size_t)sp[i + 2] * 64 + lane];
      uint2 nd = kvb[(size_t)sp[i + 3] * 64 + lane];
      proc(a); proc(b); proc(c); proc(d);
      a = na; b = nb; c = nc; d = nd;
    }
    proc(a); proc(b); proc(c); proc(d);
  }
  for (; i < len; ++i) proc(kvb[(size_t)sp[i] * 64 + lane]);

  float inv = 1.0f / (den + 1e-16f);
  unsigned int sw = qsw[(size_t)n * 128 + 64 + lane];
  float r0 = acc0 * inv + bf_lo(sw);
  float r1 = acc1 * inv + bf_hi(sw);
  if (OUTBF) {  // layer 1: relu + pack bf16 directly for layer-2 GEMM input
    r0 = fmaxf(r0, 0.f); r1 = fmaxf(r1, 0.f);
    unsigned int pkv = (unsigned int)f2bf(r0) | ((unsigned int)f2bf(r1) << 16);
    ((unsigned int*)outp)[(size_t)n * 64 + lane] = pkv;
  } else {
    ((float2*)outp)[(size_t)n * 64 + lane] = make_float2(r0, r1);
  }
}

// ---------------- launch ----------------
extern "C" void kernel_launch(void* const* d_in, const int* in_sizes, int n_in,
                              void* d_out, int out_size, void* d_ws, size_t ws_size,
                              hipStream_t stream) {
  (void)in_sizes; (void)n_in; (void)out_size; (void)ws_size;
  const float* x  = (const float*)d_in[0];
  const int*   ei = (const int*)d_in[1];
  float* out = (float*)d_out;

  char* w = (char*)d_ws;
  size_t off = 0;
  auto alloc = [&](size_t b) { void* p = w + off; off += (b + 255) & ~(size_t)255; return p; };
  int* ssrc   = (int*)alloc((size_t)N_EDGES * 4);
  int* rowp   = (int*)alloc((size_t)(N_NODES + 1) * 4);
  int* cursor = (int*)alloc((size_t)N_NODES * 4);
  int* cnt    = (int*)alloc((size_t)N_NODES * 4);
  int* part   = (int*)alloc(256 * 4);
  unsigned short* xb  = (unsigned short*)alloc((size_t)N_NODES * 128 * 2);
  unsigned short* bt  = (unsigned short*)alloc((size_t)2 * 512 * 128 * 2);
  float* bcat = (float*)alloc(2 * 512 * 4);
  unsigned short* Oqs = (unsigned short*)alloc((size_t)N_NODES * 256 * 2);
  unsigned short* Okv = (unsigned short*)alloc((size_t)N_NODES * 256 * 2);

  WPack pk;
  for (int i = 0; i < 8; ++i) { pk.W[i] = (const float*)d_in[2 + 2 * i]; pk.B[i] = (const float*)d_in[3 + 2 * i]; }

  hipMemsetAsync(cnt, 0, (size_t)N_NODES * 4, stream);
  hist_prep<<<3637, 256, 0, stream>>>(ei, cnt, pk, bt, bcat);
  scan1<<<196, 256, 0, stream>>>(cnt, rowp, part);
  scan2<<<1, 256, 0, stream>>>(part, 196);
  scan3<<<196, 256, 0, stream>>>(rowp, part, cursor);

  // ---- layer 1 gemm || CSR scatter (independent) ----
  gemm1_scatter<<<4375, 256, 0, stream>>>(x, bt, bcat, Oqs, Okv, ei, cursor, ssrc);
  edge_attn<4, true><<<12500, 256, 0, stream>>>(Oqs, Okv, rowp, ssrc, xb, 0.17677669529663689f);

  // ---- layer 2 (H=1, d=128) ----
  gemm_qkvs_bf<<<1250, 256, 0, stream>>>(xb, bt + 65536, bcat + 512, Oqs, Okv);
  edge_attn<1, false><<<12500, 256, 0, stream>>>(Oqs, Okv, rowp, ssrc, out, 0.08838834764831845f);
}